// Round 7
// baseline (537.690 us; speedup 1.0000x reference)
//
#include <hip/hip_runtime.h>

#define SEQ   2048
#define EMB   2048
#define NHEAD 16
#define HDIM  128
#define ROWSM 4096  // B*SEQ

typedef float  f32x4   __attribute__((ext_vector_type(4)));
typedef float  f32x16  __attribute__((ext_vector_type(16)));
typedef __bf16 bf16x8  __attribute__((ext_vector_type(8)));

__device__ __forceinline__ unsigned short f2bf(float f) {
  union { float f; unsigned int u; } v; v.f = f;
  return (unsigned short)((v.u + 0x7fffu + ((v.u >> 16) & 1u)) >> 16);
}
__device__ __forceinline__ unsigned int pk2(float a, float b) {
  return (unsigned int)f2bf(a) | ((unsigned int)f2bf(b) << 16);
}

__device__ __forceinline__ void gload16(const void* g, void* l) {
  __builtin_amdgcn_global_load_lds(
      (__attribute__((address_space(1))) const unsigned int*)g,
      (__attribute__((address_space(3))) unsigned int*)l,
      16, 0, 0);
}

// fp32 -> bf16 bulk convert, 4 elems/thread
__global__ void cvt_bf16(const float* __restrict__ in,
                         unsigned short* __restrict__ out, int n4) {
  int i = blockIdx.x * 256 + threadIdx.x;
  if (i >= n4) return;
  float4 v = ((const float4*)in)[i];
  ushort4 o;
  o.x = f2bf(v.x); o.y = f2bf(v.y); o.z = f2bf(v.z); o.w = f2bf(v.w);
  ((ushort4*)out)[i] = o;
}

// C = A @ B^T. A: MxK bf16 row-major, B: NxK bf16 row-major.
// 2D grid (default round-robin dispatch: per-XCD L2 set ~2 B-panels + A-rows,
// fits 4MB L2; round-6's 1D n-fastest chunk swizzle put all 16 B-panels (8MB)
// on every XCD -> +13% regression. Do not re-swizzle without m-band chunking.)
// (256,3): VGPR use 128 < cap 170 -> 3 blocks/CU, no spill.
template <int STORE_F32>
__global__ __launch_bounds__(256, 3) void gemm_nt(
    const unsigned short* __restrict__ A, const unsigned short* __restrict__ B,
    void* __restrict__ Cout, const float* __restrict__ bias,
    int M, int N, int K) {
  __shared__ __align__(16) unsigned short As[128 * 64];
  __shared__ __align__(16) unsigned short Bs[128 * 64];
  const int tid  = threadIdx.x;
  const int lane = tid & 63;
  const int w    = tid >> 6;
  const int m0 = blockIdx.y * 128;
  const int n0 = blockIdx.x * 128;
  const int wm = (w >> 1) * 64;
  const int wn = (w & 1) * 64;
  const int lg = lane >> 4;
  const int lc = lane & 15;

  f32x4 acc[4][4] = {};

  const int srow = lane >> 3;
  const int scol = (lane & 7) * 8;

  for (int k0 = 0; k0 < K; k0 += 64) {
    if (k0) __syncthreads();
#pragma unroll
    for (int ii = 0; ii < 4; ++ii) {
      int i = w * 4 + ii;
      int r = i * 8 + srow;
      gload16(A + (size_t)(m0 + r) * K + k0 + scol, (char*)As + i * 1024);
      gload16(B + (size_t)(n0 + r) * K + k0 + scol, (char*)Bs + i * 1024);
    }
    __syncthreads();
#pragma unroll
    for (int kk = 0; kk < 2; ++kk) {
      const int co = kk * 32 + lg * 8;
      bf16x8 a[4], b[4];
#pragma unroll
      for (int i = 0; i < 4; ++i)
        a[i] = *(const bf16x8*)(As + (wm + i * 16 + lc) * 64 + co);
#pragma unroll
      for (int j = 0; j < 4; ++j)
        b[j] = *(const bf16x8*)(Bs + (wn + j * 16 + lc) * 64 + co);
#pragma unroll
      for (int i = 0; i < 4; ++i)
#pragma unroll
        for (int j = 0; j < 4; ++j)
          acc[i][j] = __builtin_amdgcn_mfma_f32_16x16x32_bf16(a[i], b[j], acc[i][j], 0, 0, 0);
    }
  }

  const int rb = lg * 4;
#pragma unroll
  for (int i = 0; i < 4; ++i) {
#pragma unroll
    for (int j = 0; j < 4; ++j) {
      int col = n0 + wn + j * 16 + lc;
#pragma unroll
      for (int r = 0; r < 4; ++r) {
        int row = m0 + wm + i * 16 + rb + r;
        if (STORE_F32) {
          ((float*)Cout)[(size_t)row * N + col] = acc[i][j][r] + bias[col];
        } else {
          ((unsigned short*)Cout)[(size_t)row * N + col] = f2bf(acc[i][j][r]);
        }
      }
    }
  }
}

// Causal flash attention, swapped-QK form (round-5 proven structure, verbatim
// except launch_bounds). Grid: (SEQ/128, B*H). Block: 256 = 4 waves x 32 q-rows.
// S^T = mfma32x32(K,Q): lane&31=q, regs+hi=kv -> softmax fully in-register.
// Single-buffered LDS (32KB): round-6 dbuf+prefetch regressed (barrier drains
// vmcnt(0) incl. prefetch; m99/m100 analog). T13 defer-max.
// (256,4): kernel needs 112 VGPR < cap 128 -> 4 blocks/CU (was 2). Round-2's
// spill was the OLD 16x16 kernel (needed 124+, capped 84) — not this one.
__global__ __launch_bounds__(256, 4) void attn_causal(
    const unsigned short* __restrict__ Pq, const unsigned short* __restrict__ Pk,
    const unsigned short* __restrict__ Pv, unsigned short* __restrict__ ctx) {
  __shared__ __align__(16) unsigned short Ks[64 * 128];   // K tile [kv][d], swizzled
  __shared__ __align__(16) unsigned short Vt[128 * 64];   // V^T tile [d][kv], swizzled

  const int tid  = threadIdx.x;
  const int lane = tid & 63;
  const int w    = tid >> 6;
  const int ql   = lane & 31;
  const int hi   = lane >> 5;
  const int lg   = lane >> 4;
  const int lc   = lane & 15;

  const int bh = blockIdx.y;
  const int b  = bh >> 4;
  const int h  = bh & 15;
  const int qt = (bh & 16) ? blockIdx.x : (15 - blockIdx.x);  // work pairing
  const int q0 = qt * 128;
  const int qw = q0 + w * 32;
  const int qg = qw + ql;

  const size_t hoff = (size_t)bh * SEQ * HDIM;
  const unsigned short* Q  = Pq + hoff;
  const unsigned short* Kh = Pk + hoff;
  const unsigned short* Vh = Pv + hoff;

  // Q as B-fragments: lane holds row q=lane&31, k = d8*16 + hi*8 + j
  bf16x8 bq[8];
#pragma unroll
  for (int d8 = 0; d8 < 8; ++d8)
    bq[d8] = *(const bf16x8*)(Q + (size_t)qg * HDIM + d8 * 16 + hi * 8);

  const float NEG = -3.0e38f;
  f32x16 o[4];
#pragma unroll
  for (int dt = 0; dt < 4; ++dt)
#pragma unroll
    for (int r = 0; r < 16; ++r) o[dt][r] = 0.f;
  float m_r = NEG, l_r = 0.f;

  const float Cs   = 0.12753123161692858f;  // log2(e)/sqrt(128)
  const float TDEF = 62.7f;                 // 8 / Cs (defer-max threshold)

  const int ntiles = (q0 >> 6) + 2;
  for (int t = 0; t < ntiles; ++t) {
    const int kv0 = t * 64;
    if (t) __syncthreads();
    // ---- stage K (global_load_lds, pre-swizzled source) ----
#pragma unroll
    for (int ii = 0; ii < 4; ++ii) {
      int i = w * 4 + ii;
      int r = i * 4 + lg;
      int sd = lc ^ (r & 7);
      gload16(Kh + (size_t)(kv0 + r) * HDIM + sd * 8, (char*)Ks + i * 1024);
    }
    // ---- stage V transposed (swizzled; STATIC jj only — round-2 lesson) ----
#pragma unroll
    for (int uu = 0; uu < 2; ++uu) {
      int u = tid + uu * 256;
      int kp = u >> 4, dg = u & 15;
      int k = kp * 2, d0 = dg * 8;
      uint4 r0 = *(const uint4*)(Vh + (size_t)(kv0 + k) * HDIM + d0);
      uint4 r1 = *(const uint4*)(Vh + (size_t)(kv0 + k + 1) * HDIM + d0);
      const unsigned short* e0 = (const unsigned short*)&r0;
      const unsigned short* e1 = (const unsigned short*)&r1;
#pragma unroll
      for (int jj = 0; jj < 8; ++jj) {
        int d = d0 + jj;
        int slotswz = (k >> 3) ^ jj ^ (dg & 7);
        int byteoff = d * 128 + (slotswz << 4) + (k & 7) * 2;
        *(unsigned int*)((char*)Vt + byteoff) =
            (unsigned int)e0[jj] | ((unsigned int)e1[jj] << 16);
      }
    }
    __syncthreads();

    if (kv0 > qw + 31) continue;            // wave-uniform tile skip
    const bool s1on = (kv0 + 32 <= qw + 31);
    const bool diag = (kv0 + 63 > qw);

    // ---- S^T = K @ Q^T : lane = q, regs = kv ----
    f32x16 c0, c1;
#pragma unroll
    for (int r = 0; r < 16; ++r) { c0[r] = 0.f; c1[r] = s1on ? 0.f : NEG; }
#pragma unroll
    for (int d8 = 0; d8 < 8; ++d8) {
      bf16x8 ak = *(const bf16x8*)((const char*)Ks + ql * 256 +
                                   (((d8 * 2 + hi) ^ (ql & 7)) << 4));
      c0 = __builtin_amdgcn_mfma_f32_32x32x16_bf16(ak, bq[d8], c0, 0, 0, 0);
    }
    if (s1on) {
#pragma unroll
      for (int d8 = 0; d8 < 8; ++d8) {
        bf16x8 ak = *(const bf16x8*)((const char*)Ks + (32 + ql) * 256 +
                                     (((d8 * 2 + hi) ^ (ql & 7)) << 4));
        c1 = __builtin_amdgcn_mfma_f32_32x32x16_bf16(ak, bq[d8], c1, 0, 0, 0);
      }
    }
    // ---- causal mask: per-lane scalar compares ----
    if (diag) {
#pragma unroll
      for (int r = 0; r < 16; ++r) {
        int kvl = (r & 3) + 8 * (r >> 2) + 4 * hi;
        if (kv0 + kvl > qg) c0[r] = NEG;
        if (s1on && kv0 + 32 + kvl > qg) c1[r] = NEG;
      }
    }
    // ---- in-register softmax ----
    float rm = c0[0];
#pragma unroll
    for (int r = 1; r < 16; ++r) rm = fmaxf(rm, c0[r]);
#pragma unroll
    for (int r = 0; r < 16; ++r) rm = fmaxf(rm, c1[r]);
    rm = fmaxf(rm, __shfl_xor(rm, 32));

    if (__any(rm > m_r + TDEF)) {           // T13 defer-max
      float mnew = fmaxf(m_r, rm);
      float alpha = exp2f((m_r - mnew) * Cs);
      m_r = mnew;
      l_r *= alpha;
#pragma unroll
      for (int r = 0; r < 16; ++r) {
        float ar = __shfl(alpha, (r & 3) + 8 * (r >> 2) + 4 * hi);
#pragma unroll
        for (int dt = 0; dt < 4; ++dt) o[dt][r] *= ar;
      }
    }
#pragma unroll
    for (int r = 0; r < 16; ++r) {
      c0[r] = exp2f((c0[r] - m_r) * Cs);
      c1[r] = exp2f((c1[r] - m_r) * Cs);
    }
    float ps = 0.f;
#pragma unroll
    for (int r = 0; r < 16; ++r) ps += c0[r] + c1[r];
    ps += __shfl_xor(ps, 32);
    l_r += ps;

    // ---- repack P -> PV A-fragments, xor-32 exchange (STATIC) ----
    bf16x8 pa[4];
#pragma unroll
    for (int t4 = 0; t4 < 4; ++t4) {
      const f32x16& cc = (t4 < 2) ? c0 : c1;
      const int rA = (t4 & 1) * 8;
      unsigned int pkL0 = pk2(cc[rA + 0], cc[rA + 1]);
      unsigned int pkL1 = pk2(cc[rA + 2], cc[rA + 3]);
      unsigned int pkH0 = pk2(cc[rA + 4], cc[rA + 5]);
      unsigned int pkH1 = pk2(cc[rA + 6], cc[rA + 7]);
      unsigned int give0 = hi ? pkL0 : pkH0;
      unsigned int give1 = hi ? pkL1 : pkH1;
      unsigned int keep0 = hi ? pkH0 : pkL0;
      unsigned int keep1 = hi ? pkH1 : pkL1;
      unsigned int recv0 = __shfl_xor(give0, 32);
      unsigned int recv1 = __shfl_xor(give1, 32);
      union { unsigned int u[4]; bf16x8 v; } pu;
      pu.u[0] = hi ? recv0 : keep0;
      pu.u[1] = hi ? recv1 : keep1;
      pu.u[2] = hi ? keep0 : recv0;
      pu.u[3] = hi ? keep1 : recv1;
      pa[t4] = pu.v;
    }
    // ---- O += P @ V : lane = d, regs = q ----
#pragma unroll
    for (int t4 = 0; t4 < 4; ++t4) {
      if (diag && kv0 + t4 * 16 > qw + 31) continue;  // wave-uniform
#pragma unroll
      for (int dt = 0; dt < 4; ++dt) {
        int d = dt * 32 + ql;
        bf16x8 bv = *(const bf16x8*)((const char*)Vt + d * 128 +
                                     (((t4 * 2 + hi) ^ (d & 7) ^ ((d >> 3) & 7)) << 4));
        o[dt] = __builtin_amdgcn_mfma_f32_32x32x16_bf16(pa[t4], bv, o[dt], 0, 0, 0);
      }
    }
  }

  // ---- epilogue: normalize rows (broadcast 1/l per q-row) and store ----
  float linv = 1.0f / l_r;
  unsigned short* outp = ctx + (size_t)b * SEQ * EMB + (size_t)h * HDIM;
#pragma unroll
  for (int r = 0; r < 16; ++r) {
    int kvl = (r & 3) + 8 * (r >> 2) + 4 * hi;
    float lr = __shfl(linv, kvl);
    int qrow = qw + kvl;
#pragma unroll
    for (int dt = 0; dt < 4; ++dt)
      outp[(size_t)qrow * EMB + dt * 32 + ql] = f2bf(o[dt][r] * lr);
  }
}

extern "C" void kernel_launch(void* const* d_in, const int* in_sizes, int n_in,
                              void* d_out, int out_size, void* d_ws, size_t ws_size,
                              hipStream_t stream) {
  const float* x  = (const float*)d_in[0];
  const float* Wq = (const float*)d_in[1];
  const float* Wk = (const float*)d_in[2];
  const float* Wv = (const float*)d_in[3];
  const float* Wp = (const float*)d_in[4];
  const float* bp = (const float*)d_in[5];

  char* ws = (char*)d_ws;
  unsigned short* xb = (unsigned short*)ws;                         // 16MB, reused as ctx
  unsigned short* Wb = (unsigned short*)(ws + (size_t)(16u << 20)); // 8MB, recycled
  unsigned short* Pq = (unsigned short*)(ws + (size_t)(24u << 20));
  unsigned short* Pk = (unsigned short*)(ws + (size_t)(40u << 20));
  unsigned short* Pv = (unsigned short*)(ws + (size_t)(56u << 20));

  const int nX4 = ROWSM * EMB / 4;
  const int nW4 = EMB * EMB / 4;

  cvt_bf16<<<nX4 / 256, 256, 0, stream>>>(x, xb, nX4);

  dim3 ggrid(EMB / 128, ROWSM / 128);

  cvt_bf16<<<nW4 / 256, 256, 0, stream>>>(Wq, Wb, nW4);
  gemm_nt<0><<<ggrid, 256, 0, stream>>>(xb, Wb, Pq, nullptr, ROWSM, EMB, EMB);
  cvt_bf16<<<nW4 / 256, 256, 0, stream>>>(Wk, Wb, nW4);
  gemm_nt<0><<<ggrid, 256, 0, stream>>>(xb, Wb, Pk, nullptr, ROWSM, EMB, EMB);
  cvt_bf16<<<nW4 / 256, 256, 0, stream>>>(Wv, Wb, nW4);
  gemm_nt<0><<<ggrid, 256, 0, stream>>>(xb, Wb, Pv, nullptr, ROWSM, EMB, EMB);

  attn_causal<<<dim3(SEQ / 128, 32), 256, 0, stream>>>(Pq, Pk, Pv, xb);

  cvt_bf16<<<nW4 / 256, 256, 0, stream>>>(Wp, Wb, nW4);
  gemm_nt<1><<<ggrid, 256, 0, stream>>>(xb, Wb, d_out, bp, ROWSM, EMB, EMB);
}

// Round 8
// 302.392 us; speedup vs baseline: 1.7781x; 1.7781x over previous
//
#include <hip/hip_runtime.h>

#define SEQ   2048
#define EMB   2048
#define NHEAD 16
#define HDIM  128
#define ROWSM 4096  // B*SEQ

typedef float  f32x4   __attribute__((ext_vector_type(4)));
typedef float  f32x16  __attribute__((ext_vector_type(16)));
typedef __bf16 bf16x8  __attribute__((ext_vector_type(8)));

__device__ __forceinline__ unsigned short f2bf(float f) {
  union { float f; unsigned int u; } v; v.f = f;
  return (unsigned short)((v.u + 0x7fffu + ((v.u >> 16) & 1u)) >> 16);
}
__device__ __forceinline__ unsigned int pk2(float a, float b) {
  return (unsigned int)f2bf(a) | ((unsigned int)f2bf(b) << 16);
}

__device__ __forceinline__ void gload16(const void* g, void* l) {
  __builtin_amdgcn_global_load_lds(
      (__attribute__((address_space(1))) const unsigned int*)g,
      (__attribute__((address_space(3))) unsigned int*)l,
      16, 0, 0);
}

// fp32 -> bf16 bulk convert, 4 elems/thread
__global__ void cvt_bf16(const float* __restrict__ in,
                         unsigned short* __restrict__ out, int n4) {
  int i = blockIdx.x * 256 + threadIdx.x;
  if (i >= n4) return;
  float4 v = ((const float4*)in)[i];
  ushort4 o;
  o.x = f2bf(v.x); o.y = f2bf(v.y); o.z = f2bf(v.z); o.w = f2bf(v.w);
  ((ushort4*)out)[i] = o;
}

// C = A @ B^T. A: MxK bf16 row-major, B: NxK bf16 row-major.
// LAUNCH BOUNDS LADDER (empirical, this toolchain): arg2 -> VGPR cap 128,
// arg3 -> cap ~85, arg4 -> cap 64. This kernel uses 128 VGPR -> arg MUST be 2.
// 2D grid, default dispatch (round-6's 1D n-fastest XCD chunking regressed).
template <int STORE_F32>
__global__ __launch_bounds__(256, 2) void gemm_nt(
    const unsigned short* __restrict__ A, const unsigned short* __restrict__ B,
    void* __restrict__ Cout, const float* __restrict__ bias,
    int M, int N, int K) {
  __shared__ __align__(16) unsigned short As[128 * 64];
  __shared__ __align__(16) unsigned short Bs[128 * 64];
  const int tid  = threadIdx.x;
  const int lane = tid & 63;
  const int w    = tid >> 6;
  const int m0 = blockIdx.y * 128;
  const int n0 = blockIdx.x * 128;
  const int wm = (w >> 1) * 64;
  const int wn = (w & 1) * 64;
  const int lg = lane >> 4;
  const int lc = lane & 15;

  f32x4 acc[4][4] = {};

  const int srow = lane >> 3;
  const int scol = (lane & 7) * 8;

  for (int k0 = 0; k0 < K; k0 += 64) {
    if (k0) __syncthreads();
#pragma unroll
    for (int ii = 0; ii < 4; ++ii) {
      int i = w * 4 + ii;
      int r = i * 8 + srow;
      gload16(A + (size_t)(m0 + r) * K + k0 + scol, (char*)As + i * 1024);
      gload16(B + (size_t)(n0 + r) * K + k0 + scol, (char*)Bs + i * 1024);
    }
    __syncthreads();
#pragma unroll
    for (int kk = 0; kk < 2; ++kk) {
      const int co = kk * 32 + lg * 8;
      bf16x8 a[4], b[4];
#pragma unroll
      for (int i = 0; i < 4; ++i)
        a[i] = *(const bf16x8*)(As + (wm + i * 16 + lc) * 64 + co);
#pragma unroll
      for (int j = 0; j < 4; ++j)
        b[j] = *(const bf16x8*)(Bs + (wn + j * 16 + lc) * 64 + co);
#pragma unroll
      for (int i = 0; i < 4; ++i)
#pragma unroll
        for (int j = 0; j < 4; ++j)
          acc[i][j] = __builtin_amdgcn_mfma_f32_16x16x32_bf16(a[i], b[j], acc[i][j], 0, 0, 0);
    }
  }

  const int rb = lg * 4;
#pragma unroll
  for (int i = 0; i < 4; ++i) {
#pragma unroll
    for (int j = 0; j < 4; ++j) {
      int col = n0 + wn + j * 16 + lc;
#pragma unroll
      for (int r = 0; r < 4; ++r) {
        int row = m0 + wm + i * 16 + rb + r;
        if (STORE_F32) {
          ((float*)Cout)[(size_t)row * N + col] = acc[i][j][r] + bias[col];
        } else {
          ((unsigned short*)Cout)[(size_t)row * N + col] = f2bf(acc[i][j][r]);
        }
      }
    }
  }
}

// Causal flash attention, swapped-QK form (round-5 proven, 100us). Grid: 512
// blocks 1D, head-grouped per XCD: xcd = bid&7, head = xcd*4 + hh, so all 16
// q-tiles of a head share one XCD -> per-XCD K/V set = 4 heads = 4MB ~ L2.
// CU-level balance: qt = (hh>=2) ? 15-j : j (CU gets qt + (15-qt) pair).
// Single-buffered LDS (dbuf regressed: barrier drains vmcnt0 incl. prefetch).
// __launch_bounds__(256,2) REQUIRED: arg3 caps VGPR 85, arg4 caps 64 -> the
// 64-VGPR o-accumulator spills (round-7: FETCH 111->388MB, 3.3x slower).
__global__ __launch_bounds__(256, 2) void attn_causal(
    const unsigned short* __restrict__ Pq, const unsigned short* __restrict__ Pk,
    const unsigned short* __restrict__ Pv, unsigned short* __restrict__ ctx) {
  __shared__ __align__(16) unsigned short Ks[64 * 128];   // K tile [kv][d], swizzled
  __shared__ __align__(16) unsigned short Vt[128 * 64];   // V^T tile [d][kv], swizzled

  const int tid  = threadIdx.x;
  const int lane = tid & 63;
  const int w    = tid >> 6;
  const int ql   = lane & 31;
  const int hi   = lane >> 5;
  const int lg   = lane >> 4;
  const int lc   = lane & 15;

  // head-grouped XCD decode
  const int bid = blockIdx.x;
  const int xcd = bid & 7;
  const int j   = bid >> 3;         // 0..63 within XCD
  const int hh  = j >> 4;           // 0..3: which head of this XCD
  const int bh  = xcd * 4 + hh;     // 0..31
  const int b   = bh >> 4;
  const int h   = bh & 15;
  const int qtr = j & 15;
  const int qt  = (hh >= 2) ? (15 - qtr) : qtr;   // per-CU work pairing
  const int q0 = qt * 128;
  const int qw = q0 + w * 32;
  const int qg = qw + ql;

  const size_t hoff = (size_t)bh * SEQ * HDIM;
  const unsigned short* Q  = Pq + hoff;
  const unsigned short* Kh = Pk + hoff;
  const unsigned short* Vh = Pv + hoff;

  // Q as B-fragments: lane holds row q=lane&31, k = d8*16 + hi*8 + j
  bf16x8 bq[8];
#pragma unroll
  for (int d8 = 0; d8 < 8; ++d8)
    bq[d8] = *(const bf16x8*)(Q + (size_t)qg * HDIM + d8 * 16 + hi * 8);

  const float NEG = -3.0e38f;
  f32x16 o[4];
#pragma unroll
  for (int dt = 0; dt < 4; ++dt)
#pragma unroll
    for (int r = 0; r < 16; ++r) o[dt][r] = 0.f;
  float m_r = NEG, l_r = 0.f;

  const float Cs   = 0.12753123161692858f;  // log2(e)/sqrt(128)
  const float TDEF = 62.7f;                 // 8 / Cs (defer-max threshold)

  const int ntiles = (q0 >> 6) + 2;
  for (int t = 0; t < ntiles; ++t) {
    const int kv0 = t * 64;
    if (t) __syncthreads();
    // ---- stage K (global_load_lds, pre-swizzled source) ----
#pragma unroll
    for (int ii = 0; ii < 4; ++ii) {
      int i = w * 4 + ii;
      int r = i * 4 + lg;
      int sd = lc ^ (r & 7);
      gload16(Kh + (size_t)(kv0 + r) * HDIM + sd * 8, (char*)Ks + i * 1024);
    }
    // ---- stage V transposed (swizzled; STATIC jj only — round-2 lesson) ----
#pragma unroll
    for (int uu = 0; uu < 2; ++uu) {
      int u = tid + uu * 256;
      int kp = u >> 4, dg = u & 15;
      int k = kp * 2, d0 = dg * 8;
      uint4 r0 = *(const uint4*)(Vh + (size_t)(kv0 + k) * HDIM + d0);
      uint4 r1 = *(const uint4*)(Vh + (size_t)(kv0 + k + 1) * HDIM + d0);
      const unsigned short* e0 = (const unsigned short*)&r0;
      const unsigned short* e1 = (const unsigned short*)&r1;
#pragma unroll
      for (int jj = 0; jj < 8; ++jj) {
        int d = d0 + jj;
        int slotswz = (k >> 3) ^ jj ^ (dg & 7);
        int byteoff = d * 128 + (slotswz << 4) + (k & 7) * 2;
        *(unsigned int*)((char*)Vt + byteoff) =
            (unsigned int)e0[jj] | ((unsigned int)e1[jj] << 16);
      }
    }
    __syncthreads();

    if (kv0 > qw + 31) continue;            // wave-uniform tile skip
    const bool s1on = (kv0 + 32 <= qw + 31);
    const bool diag = (kv0 + 63 > qw);

    // ---- S^T = K @ Q^T : lane = q, regs = kv ----
    f32x16 c0, c1;
#pragma unroll
    for (int r = 0; r < 16; ++r) { c0[r] = 0.f; c1[r] = s1on ? 0.f : NEG; }
#pragma unroll
    for (int d8 = 0; d8 < 8; ++d8) {
      bf16x8 ak = *(const bf16x8*)((const char*)Ks + ql * 256 +
                                   (((d8 * 2 + hi) ^ (ql & 7)) << 4));
      c0 = __builtin_amdgcn_mfma_f32_32x32x16_bf16(ak, bq[d8], c0, 0, 0, 0);
    }
    if (s1on) {
#pragma unroll
      for (int d8 = 0; d8 < 8; ++d8) {
        bf16x8 ak = *(const bf16x8*)((const char*)Ks + (32 + ql) * 256 +
                                     (((d8 * 2 + hi) ^ (ql & 7)) << 4));
        c1 = __builtin_amdgcn_mfma_f32_32x32x16_bf16(ak, bq[d8], c1, 0, 0, 0);
      }
    }
    // ---- causal mask: per-lane scalar compares ----
    if (diag) {
#pragma unroll
      for (int r = 0; r < 16; ++r) {
        int kvl = (r & 3) + 8 * (r >> 2) + 4 * hi;
        if (kv0 + kvl > qg) c0[r] = NEG;
        if (s1on && kv0 + 32 + kvl > qg) c1[r] = NEG;
      }
    }
    // ---- in-register softmax ----
    float rm = c0[0];
#pragma unroll
    for (int r = 1; r < 16; ++r) rm = fmaxf(rm, c0[r]);
#pragma unroll
    for (int r = 0; r < 16; ++r) rm = fmaxf(rm, c1[r]);
    rm = fmaxf(rm, __shfl_xor(rm, 32));

    if (__any(rm > m_r + TDEF)) {           // T13 defer-max
      float mnew = fmaxf(m_r, rm);
      float alpha = exp2f((m_r - mnew) * Cs);
      m_r = mnew;
      l_r *= alpha;
#pragma unroll
      for (int r = 0; r < 16; ++r) {
        float ar = __shfl(alpha, (r & 3) + 8 * (r >> 2) + 4 * hi);
#pragma unroll
        for (int dt = 0; dt < 4; ++dt) o[dt][r] *= ar;
      }
    }
#pragma unroll
    for (int r = 0; r < 16; ++r) {
      c0[r] = exp2f((c0[r] - m_r) * Cs);
      c1[r] = exp2f((c1[r] - m_r) * Cs);
    }
    float ps = 0.f;
#pragma unroll
    for (int r = 0; r < 16; ++r) ps += c0[r] + c1[r];
    ps += __shfl_xor(ps, 32);
    l_r += ps;

    // ---- repack P -> PV A-fragments, xor-32 exchange (STATIC) ----
    bf16x8 pa[4];
#pragma unroll
    for (int t4 = 0; t4 < 4; ++t4) {
      const f32x16& cc = (t4 < 2) ? c0 : c1;
      const int rA = (t4 & 1) * 8;
      unsigned int pkL0 = pk2(cc[rA + 0], cc[rA + 1]);
      unsigned int pkL1 = pk2(cc[rA + 2], cc[rA + 3]);
      unsigned int pkH0 = pk2(cc[rA + 4], cc[rA + 5]);
      unsigned int pkH1 = pk2(cc[rA + 6], cc[rA + 7]);
      unsigned int give0 = hi ? pkL0 : pkH0;
      unsigned int give1 = hi ? pkL1 : pkH1;
      unsigned int keep0 = hi ? pkH0 : pkL0;
      unsigned int keep1 = hi ? pkH1 : pkL1;
      unsigned int recv0 = __shfl_xor(give0, 32);
      unsigned int recv1 = __shfl_xor(give1, 32);
      union { unsigned int u[4]; bf16x8 v; } pu;
      pu.u[0] = hi ? recv0 : keep0;
      pu.u[1] = hi ? recv1 : keep1;
      pu.u[2] = hi ? keep0 : recv0;
      pu.u[3] = hi ? keep1 : recv1;
      pa[t4] = pu.v;
    }
    // ---- O += P @ V : lane = d, regs = q ----
#pragma unroll
    for (int t4 = 0; t4 < 4; ++t4) {
      if (diag && kv0 + t4 * 16 > qw + 31) continue;  // wave-uniform
#pragma unroll
      for (int dt = 0; dt < 4; ++dt) {
        int d = dt * 32 + ql;
        bf16x8 bv = *(const bf16x8*)((const char*)Vt + d * 128 +
                                     (((t4 * 2 + hi) ^ (d & 7) ^ ((d >> 3) & 7)) << 4));
        o[dt] = __builtin_amdgcn_mfma_f32_32x32x16_bf16(pa[t4], bv, o[dt], 0, 0, 0);
      }
    }
  }

  // ---- epilogue: normalize rows (broadcast 1/l per q-row) and store ----
  float linv = 1.0f / l_r;
  unsigned short* outp = ctx + (size_t)b * SEQ * EMB + (size_t)h * HDIM;
#pragma unroll
  for (int r = 0; r < 16; ++r) {
    int kvl = (r & 3) + 8 * (r >> 2) + 4 * hi;
    float lr = __shfl(linv, kvl);
    int qrow = qw + kvl;
#pragma unroll
    for (int dt = 0; dt < 4; ++dt)
      outp[(size_t)qrow * EMB + dt * 32 + ql] = f2bf(o[dt][r] * lr);
  }
}

extern "C" void kernel_launch(void* const* d_in, const int* in_sizes, int n_in,
                              void* d_out, int out_size, void* d_ws, size_t ws_size,
                              hipStream_t stream) {
  const float* x  = (const float*)d_in[0];
  const float* Wq = (const float*)d_in[1];
  const float* Wk = (const float*)d_in[2];
  const float* Wv = (const float*)d_in[3];
  const float* Wp = (const float*)d_in[4];
  const float* bp = (const float*)d_in[5];

  char* ws = (char*)d_ws;
  unsigned short* xb = (unsigned short*)ws;                         // 16MB, reused as ctx
  unsigned short* Wb = (unsigned short*)(ws + (size_t)(16u << 20)); // 8MB, recycled
  unsigned short* Pq = (unsigned short*)(ws + (size_t)(24u << 20));
  unsigned short* Pk = (unsigned short*)(ws + (size_t)(40u << 20));
  unsigned short* Pv = (unsigned short*)(ws + (size_t)(56u << 20));

  const int nX4 = ROWSM * EMB / 4;
  const int nW4 = EMB * EMB / 4;

  cvt_bf16<<<nX4 / 256, 256, 0, stream>>>(x, xb, nX4);

  dim3 ggrid(EMB / 128, ROWSM / 128);

  cvt_bf16<<<nW4 / 256, 256, 0, stream>>>(Wq, Wb, nW4);
  gemm_nt<0><<<ggrid, 256, 0, stream>>>(xb, Wb, Pq, nullptr, ROWSM, EMB, EMB);
  cvt_bf16<<<nW4 / 256, 256, 0, stream>>>(Wk, Wb, nW4);
  gemm_nt<0><<<ggrid, 256, 0, stream>>>(xb, Wb, Pk, nullptr, ROWSM, EMB, EMB);
  cvt_bf16<<<nW4 / 256, 256, 0, stream>>>(Wv, Wb, nW4);
  gemm_nt<0><<<ggrid, 256, 0, stream>>>(xb, Wb, Pv, nullptr, ROWSM, EMB, EMB);

  attn_causal<<<512, 256, 0, stream>>>(Pq, Pk, Pv, xb);

  cvt_bf16<<<nW4 / 256, 256, 0, stream>>>(Wp, Wb, nW4);
  gemm_nt<1><<<ggrid, 256, 0, stream>>>(xb, Wb, d_out, bp, ROWSM, EMB, EMB);
}

// Round 9
// 286.778 us; speedup vs baseline: 1.8749x; 1.0544x over previous
//
#include <hip/hip_runtime.h>

#define SEQ   2048
#define EMB   2048
#define NHEAD 16
#define HDIM  128
#define ROWSM 4096  // B*SEQ

typedef float  f32x4   __attribute__((ext_vector_type(4)));
typedef float  f32x16  __attribute__((ext_vector_type(16)));
typedef __bf16 bf16x8  __attribute__((ext_vector_type(8)));

__device__ __forceinline__ unsigned short f2bf(float f) {
  union { float f; unsigned int u; } v; v.f = f;
  return (unsigned short)((v.u + 0x7fffu + ((v.u >> 16) & 1u)) >> 16);
}
__device__ __forceinline__ unsigned int pk2(float a, float b) {
  return (unsigned int)f2bf(a) | ((unsigned int)f2bf(b) << 16);
}

__device__ __forceinline__ void gload16(const void* g, void* l) {
  __builtin_amdgcn_global_load_lds(
      (__attribute__((address_space(1))) const unsigned int*)g,
      (__attribute__((address_space(3))) unsigned int*)l,
      16, 0, 0);
}

// fp32 -> bf16 bulk convert, 4 elems/thread
__global__ void cvt_bf16(const float* __restrict__ in,
                         unsigned short* __restrict__ out, int n4) {
  int i = blockIdx.x * 256 + threadIdx.x;
  if (i >= n4) return;
  float4 v = ((const float4*)in)[i];
  ushort4 o;
  o.x = f2bf(v.x); o.y = f2bf(v.y); o.z = f2bf(v.z); o.w = f2bf(v.w);
  ((ushort4*)out)[i] = o;
}

// three same-size fp32->bf16 converts in one launch (z selects)
__global__ void cvt_bf16_3(const float* __restrict__ i0, const float* __restrict__ i1,
                           const float* __restrict__ i2, unsigned short* __restrict__ o0,
                           unsigned short* __restrict__ o1, unsigned short* __restrict__ o2,
                           int n4) {
  const float* in = (blockIdx.z == 0) ? i0 : (blockIdx.z == 1) ? i1 : i2;
  unsigned short* out = (blockIdx.z == 0) ? o0 : (blockIdx.z == 1) ? o1 : o2;
  int i = blockIdx.x * 256 + threadIdx.x;
  if (i >= n4) return;
  float4 v = ((const float4*)in)[i];
  ushort4 o;
  o.x = f2bf(v.x); o.y = f2bf(v.y); o.z = f2bf(v.z); o.w = f2bf(v.w);
  ((ushort4*)out)[i] = o;
}

// Fused QKV: grid (N/128, M/128, 3); z selects W and output slice.
// Body identical to the proven 128x128 gemm_nt (launch_bounds ladder:
// arg2 -> VGPR cap 128; this kernel uses 128 -> arg MUST be 2).
__global__ __launch_bounds__(256, 2) void gemm_qkv(
    const unsigned short* __restrict__ A,
    const unsigned short* __restrict__ B0, const unsigned short* __restrict__ B1,
    const unsigned short* __restrict__ B2, unsigned short* __restrict__ Cbase) {
  __shared__ __align__(16) unsigned short As[128 * 64];
  __shared__ __align__(16) unsigned short Bs[128 * 64];
  const unsigned short* Bm = (blockIdx.z == 0) ? B0 : (blockIdx.z == 1) ? B1 : B2;
  unsigned short* C = Cbase + (size_t)blockIdx.z * ROWSM * EMB;

  const int tid  = threadIdx.x;
  const int lane = tid & 63;
  const int w    = tid >> 6;
  const int m0 = blockIdx.y * 128;
  const int n0 = blockIdx.x * 128;
  const int wm = (w >> 1) * 64;
  const int wn = (w & 1) * 64;
  const int lg = lane >> 4;
  const int lc = lane & 15;

  f32x4 acc[4][4] = {};
  const int srow = lane >> 3;
  const int scol = (lane & 7) * 8;

  for (int k0 = 0; k0 < EMB; k0 += 64) {
    if (k0) __syncthreads();
#pragma unroll
    for (int ii = 0; ii < 4; ++ii) {
      int i = w * 4 + ii;
      int r = i * 8 + srow;
      gload16(A  + (size_t)(m0 + r) * EMB + k0 + scol, (char*)As + i * 1024);
      gload16(Bm + (size_t)(n0 + r) * EMB + k0 + scol, (char*)Bs + i * 1024);
    }
    __syncthreads();
#pragma unroll
    for (int kk = 0; kk < 2; ++kk) {
      const int co = kk * 32 + lg * 8;
      bf16x8 a[4], b[4];
#pragma unroll
      for (int i = 0; i < 4; ++i)
        a[i] = *(const bf16x8*)(As + (wm + i * 16 + lc) * 64 + co);
#pragma unroll
      for (int j = 0; j < 4; ++j)
        b[j] = *(const bf16x8*)(Bs + (wn + j * 16 + lc) * 64 + co);
#pragma unroll
      for (int i = 0; i < 4; ++i)
#pragma unroll
        for (int j = 0; j < 4; ++j)
          acc[i][j] = __builtin_amdgcn_mfma_f32_16x16x32_bf16(a[i], b[j], acc[i][j], 0, 0, 0);
    }
  }

  const int rb = lg * 4;
#pragma unroll
  for (int i = 0; i < 4; ++i)
#pragma unroll
    for (int j = 0; j < 4; ++j) {
      int col = n0 + wn + j * 16 + lc;
#pragma unroll
      for (int r = 0; r < 4; ++r) {
        int row = m0 + wm + i * 16 + rb + r;
        C[(size_t)row * EMB + col] = f2bf(acc[i][j][r]);
      }
    }
}

// Final projection GEMM: C_f32 = A @ B^T + bias.
__global__ __launch_bounds__(256, 2) void gemm_p(
    const unsigned short* __restrict__ A, const unsigned short* __restrict__ B,
    float* __restrict__ Cout, const float* __restrict__ bias) {
  __shared__ __align__(16) unsigned short As[128 * 64];
  __shared__ __align__(16) unsigned short Bs[128 * 64];
  const int tid  = threadIdx.x;
  const int lane = tid & 63;
  const int w    = tid >> 6;
  const int m0 = blockIdx.y * 128;
  const int n0 = blockIdx.x * 128;
  const int wm = (w >> 1) * 64;
  const int wn = (w & 1) * 64;
  const int lg = lane >> 4;
  const int lc = lane & 15;

  f32x4 acc[4][4] = {};
  const int srow = lane >> 3;
  const int scol = (lane & 7) * 8;

  for (int k0 = 0; k0 < EMB; k0 += 64) {
    if (k0) __syncthreads();
#pragma unroll
    for (int ii = 0; ii < 4; ++ii) {
      int i = w * 4 + ii;
      int r = i * 8 + srow;
      gload16(A + (size_t)(m0 + r) * EMB + k0 + scol, (char*)As + i * 1024);
      gload16(B + (size_t)(n0 + r) * EMB + k0 + scol, (char*)Bs + i * 1024);
    }
    __syncthreads();
#pragma unroll
    for (int kk = 0; kk < 2; ++kk) {
      const int co = kk * 32 + lg * 8;
      bf16x8 a[4], b[4];
#pragma unroll
      for (int i = 0; i < 4; ++i)
        a[i] = *(const bf16x8*)(As + (wm + i * 16 + lc) * 64 + co);
#pragma unroll
      for (int j = 0; j < 4; ++j)
        b[j] = *(const bf16x8*)(Bs + (wn + j * 16 + lc) * 64 + co);
#pragma unroll
      for (int i = 0; i < 4; ++i)
#pragma unroll
        for (int j = 0; j < 4; ++j)
          acc[i][j] = __builtin_amdgcn_mfma_f32_16x16x32_bf16(a[i], b[j], acc[i][j], 0, 0, 0);
    }
  }

  const int rb = lg * 4;
#pragma unroll
  for (int i = 0; i < 4; ++i)
#pragma unroll
    for (int j = 0; j < 4; ++j) {
      int col = n0 + wn + j * 16 + lc;
#pragma unroll
      for (int r = 0; r < 4; ++r) {
        int row = m0 + wm + i * 16 + rb + r;
        Cout[(size_t)row * EMB + col] = acc[i][j][r] + bias[col];
      }
    }
}

// Causal flash attention, swapped-QK form, KVBLK=128 (two 64-halves per
// stage+barrier pair -> half the barriers), head-grouped XCD mapping
// (round-8: FETCH 111->25MB), T5 setprio around MFMA clusters, T13 defer-max.
// Register peak kept at round-5 level: V staged in two vr[4] passes with
// #pragma unroll 1 (round-6 lesson: long-lived vr spills).
// __launch_bounds__(256,2) REQUIRED (ladder: arg3->85, arg4->64 -> o[] spills).
__global__ __launch_bounds__(256, 2) void attn_causal(
    const unsigned short* __restrict__ Pq, const unsigned short* __restrict__ Pk,
    const unsigned short* __restrict__ Pv, unsigned short* __restrict__ ctx) {
  __shared__ __align__(16) unsigned short Ks[128 * 128];   // K [kv][d], swizzled (32KB)
  __shared__ __align__(16) unsigned short Vt[128 * 128];   // V^T [d][kv], swizzled (32KB)

  const int tid  = threadIdx.x;
  const int lane = tid & 63;
  const int w    = tid >> 6;
  const int ql   = lane & 31;
  const int hi   = lane >> 5;
  const int lg   = lane >> 4;
  const int lc   = lane & 15;

  // head-grouped XCD decode: all 16 q-tiles of a head share one XCD
  const int bid = blockIdx.x;
  const int xcd = bid & 7;
  const int jj_ = bid >> 3;
  const int hh  = jj_ >> 4;
  const int bh  = xcd * 4 + hh;
  const int b   = bh >> 4;
  const int h   = bh & 15;
  const int qtr = jj_ & 15;
  const int qt  = (hh >= 2) ? (15 - qtr) : qtr;   // per-CU work pairing
  const int q0 = qt * 128;
  const int qw = q0 + w * 32;
  const int qg = qw + ql;

  const size_t hoff = (size_t)bh * SEQ * HDIM;
  const unsigned short* Q  = Pq + hoff;
  const unsigned short* Kh = Pk + hoff;
  const unsigned short* Vh = Pv + hoff;

  // Q as B-fragments: lane holds row q=lane&31, k = d8*16 + hi*8 + j
  bf16x8 bq[8];
#pragma unroll
  for (int d8 = 0; d8 < 8; ++d8)
    bq[d8] = *(const bf16x8*)(Q + (size_t)qg * HDIM + d8 * 16 + hi * 8);

  const float NEG = -3.0e38f;
  f32x16 o[4];
#pragma unroll
  for (int dt = 0; dt < 4; ++dt)
#pragma unroll
    for (int r = 0; r < 16; ++r) o[dt][r] = 0.f;
  float m_r = NEG, l_r = 0.f;

  const float Cs   = 0.12753123161692858f;  // log2(e)/sqrt(128)
  const float TDEF = 62.7f;                 // 8 / Cs

  const int nt128 = qt + 1;
  for (int tt = 0; tt < nt128; ++tt) {
    const int kv0 = tt * 128;
    if (tt) __syncthreads();
    // ---- stage K: 128 rows via global_load_lds (pre-swizzled source) ----
#pragma unroll
    for (int ii = 0; ii < 8; ++ii) {
      int i = w * 8 + ii;                 // 32 chunks of 1KB (4 rows each)
      int r = i * 4 + lg;
      int sd = lc ^ (r & 7);
      gload16(Kh + (size_t)(kv0 + r) * HDIM + sd * 8, (char*)Ks + i * 1024);
    }
    // ---- stage V transposed: two 64-row passes, vr[4] transient each ----
#pragma unroll 1
    for (int hv = 0; hv < 2; ++hv) {
      uint4 vr[4];
      const unsigned short* Vs = Vh + (size_t)(kv0 + hv * 64) * HDIM;
#pragma unroll
      for (int uu = 0; uu < 2; ++uu) {
        int u = tid + uu * 256;
        int kp = u >> 4, dg = u & 15;
        int k = kp * 2, d0 = dg * 8;
        vr[uu * 2]     = *(const uint4*)(Vs + (size_t)k * HDIM + d0);
        vr[uu * 2 + 1] = *(const uint4*)(Vs + (size_t)(k + 1) * HDIM + d0);
      }
#pragma unroll
      for (int uu = 0; uu < 2; ++uu) {
        int u = tid + uu * 256;
        int kp = u >> 4, dg = u & 15;
        int k = kp * 2, d0 = dg * 8;
        const unsigned short* e0 = (const unsigned short*)&vr[uu * 2];
        const unsigned short* e1 = (const unsigned short*)&vr[uu * 2 + 1];
#pragma unroll
        for (int jj = 0; jj < 8; ++jj) {  // STATIC index only
          int d = d0 + jj;
          int slot = ((hv << 3) | (k >> 3)) ^ jj ^ (dg & 7);
          int byteoff = d * 256 + (slot << 4) + (k & 7) * 2;
          *(unsigned int*)((char*)Vt + byteoff) =
              (unsigned int)e0[jj] | ((unsigned int)e1[jj] << 16);
        }
      }
    }
    __syncthreads();

    // ---- compute: two 64-halves against the staged 128 rows ----
#pragma unroll 1
    for (int hf = 0; hf < 2; ++hf) {
      const int kv0h = kv0 + hf * 64;
      if (kv0h > qw + 31) continue;       // wave-uniform half skip
      const bool s1on = (kv0h + 32 <= qw + 31);
      const bool diag = (kv0h + 63 > qw);
      const char* ksb = (const char*)Ks + hf * 64 * 256;

      // S^T = K @ Q^T : lane = q, regs = kv
      f32x16 c0, c1;
#pragma unroll
      for (int r = 0; r < 16; ++r) { c0[r] = 0.f; c1[r] = s1on ? 0.f : NEG; }
      __builtin_amdgcn_s_setprio(1);
#pragma unroll
      for (int d8 = 0; d8 < 8; ++d8) {
        bf16x8 ak = *(const bf16x8*)(ksb + ql * 256 +
                                     (((d8 * 2 + hi) ^ (ql & 7)) << 4));
        c0 = __builtin_amdgcn_mfma_f32_32x32x16_bf16(ak, bq[d8], c0, 0, 0, 0);
      }
      if (s1on) {
#pragma unroll
        for (int d8 = 0; d8 < 8; ++d8) {
          bf16x8 ak = *(const bf16x8*)(ksb + (32 + ql) * 256 +
                                       (((d8 * 2 + hi) ^ (ql & 7)) << 4));
          c1 = __builtin_amdgcn_mfma_f32_32x32x16_bf16(ak, bq[d8], c1, 0, 0, 0);
        }
      }
      __builtin_amdgcn_s_setprio(0);

      // causal mask: per-lane scalar compares
      if (diag) {
#pragma unroll
        for (int r = 0; r < 16; ++r) {
          int kvl = (r & 3) + 8 * (r >> 2) + 4 * hi;
          if (kv0h + kvl > qg) c0[r] = NEG;
          if (s1on && kv0h + 32 + kvl > qg) c1[r] = NEG;
        }
      }
      // in-register softmax
      float rm = c0[0];
#pragma unroll
      for (int r = 1; r < 16; ++r) rm = fmaxf(rm, c0[r]);
#pragma unroll
      for (int r = 0; r < 16; ++r) rm = fmaxf(rm, c1[r]);
      rm = fmaxf(rm, __shfl_xor(rm, 32));

      if (__any(rm > m_r + TDEF)) {       // T13 defer-max
        float mnew = fmaxf(m_r, rm);
        float alpha = exp2f((m_r - mnew) * Cs);
        m_r = mnew;
        l_r *= alpha;
#pragma unroll
        for (int r = 0; r < 16; ++r) {
          float ar = __shfl(alpha, (r & 3) + 8 * (r >> 2) + 4 * hi);
#pragma unroll
          for (int dt = 0; dt < 4; ++dt) o[dt][r] *= ar;
        }
      }
#pragma unroll
      for (int r = 0; r < 16; ++r) {
        c0[r] = exp2f((c0[r] - m_r) * Cs);
        c1[r] = exp2f((c1[r] - m_r) * Cs);
      }
      float ps = 0.f;
#pragma unroll
      for (int r = 0; r < 16; ++r) ps += c0[r] + c1[r];
      ps += __shfl_xor(ps, 32);
      l_r += ps;

      // repack P -> PV A-fragments, xor-32 exchange (STATIC)
      bf16x8 pa[4];
#pragma unroll
      for (int t4 = 0; t4 < 4; ++t4) {
        const f32x16& cc = (t4 < 2) ? c0 : c1;
        const int rA = (t4 & 1) * 8;
        unsigned int pkL0 = pk2(cc[rA + 0], cc[rA + 1]);
        unsigned int pkL1 = pk2(cc[rA + 2], cc[rA + 3]);
        unsigned int pkH0 = pk2(cc[rA + 4], cc[rA + 5]);
        unsigned int pkH1 = pk2(cc[rA + 6], cc[rA + 7]);
        unsigned int give0 = hi ? pkL0 : pkH0;
        unsigned int give1 = hi ? pkL1 : pkH1;
        unsigned int keep0 = hi ? pkH0 : pkL0;
        unsigned int keep1 = hi ? pkH1 : pkL1;
        unsigned int recv0 = __shfl_xor(give0, 32);
        unsigned int recv1 = __shfl_xor(give1, 32);
        union { unsigned int u[4]; bf16x8 v; } pu;
        pu.u[0] = hi ? recv0 : keep0;
        pu.u[1] = hi ? recv1 : keep1;
        pu.u[2] = hi ? keep0 : recv0;
        pu.u[3] = hi ? keep1 : recv1;
        pa[t4] = pu.v;
      }
      // O += P @ V : lane = d, regs = q
      __builtin_amdgcn_s_setprio(1);
#pragma unroll
      for (int t4 = 0; t4 < 4; ++t4) {
        if (diag && kv0h + t4 * 16 > qw + 31) continue;  // wave-uniform
#pragma unroll
        for (int dt = 0; dt < 4; ++dt) {
          int d = dt * 32 + ql;
          int slot = ((hf << 3) | (t4 << 1) | hi) ^ (d & 7) ^ ((d >> 3) & 7);
          bf16x8 bv = *(const bf16x8*)((const char*)Vt + d * 256 + (slot << 4));
          o[dt] = __builtin_amdgcn_mfma_f32_32x32x16_bf16(pa[t4], bv, o[dt], 0, 0, 0);
        }
      }
      __builtin_amdgcn_s_setprio(0);
    }
  }

  // ---- epilogue: normalize rows (broadcast 1/l per q-row) and store ----
  float linv = 1.0f / l_r;
  unsigned short* outp = ctx + (size_t)b * SEQ * EMB + (size_t)h * HDIM;
#pragma unroll
  for (int r = 0; r < 16; ++r) {
    int kvl = (r & 3) + 8 * (r >> 2) + 4 * hi;
    float lr = __shfl(linv, kvl);
    int qrow = qw + kvl;
#pragma unroll
    for (int dt = 0; dt < 4; ++dt)
      outp[(size_t)qrow * EMB + dt * 32 + ql] = f2bf(o[dt][r] * lr);
  }
}

extern "C" void kernel_launch(void* const* d_in, const int* in_sizes, int n_in,
                              void* d_out, int out_size, void* d_ws, size_t ws_size,
                              hipStream_t stream) {
  const float* x  = (const float*)d_in[0];
  const float* Wq = (const float*)d_in[1];
  const float* Wk = (const float*)d_in[2];
  const float* Wv = (const float*)d_in[3];
  const float* Wp = (const float*)d_in[4];
  const float* bp = (const float*)d_in[5];

  char* ws = (char*)d_ws;
  unsigned short* xb = (unsigned short*)ws;                         // 16MB, reused as ctx
  unsigned short* Wb = (unsigned short*)(ws + (size_t)(16u << 20)); // 8MB (Wq, then Wp)
  unsigned short* Pq = (unsigned short*)(ws + (size_t)(24u << 20)); // 3x16MB contiguous
  unsigned short* Pk = (unsigned short*)(ws + (size_t)(40u << 20));
  unsigned short* Pv = (unsigned short*)(ws + (size_t)(56u << 20));
  // d_out (33.5MB fp32) is fully rewritten by the final GEMM -> its first
  // 16MB doubles as scratch for Wv/Wk bf16 during the QKV phase.
  unsigned short* WvS = (unsigned short*)d_out;
  unsigned short* WkS = (unsigned short*)d_out + (size_t)4 * 1024 * 1024;

  const int nX4 = ROWSM * EMB / 4;
  const int nW4 = EMB * EMB / 4;

  cvt_bf16<<<nX4 / 256, 256, 0, stream>>>(x, xb, nX4);
  cvt_bf16_3<<<dim3(nW4 / 256, 1, 3), 256, 0, stream>>>(Wq, Wk, Wv, Wb, WkS, WvS, nW4);

  gemm_qkv<<<dim3(EMB / 128, ROWSM / 128, 3), 256, 0, stream>>>(xb, Wb, WkS, WvS, Pq);

  attn_causal<<<512, 256, 0, stream>>>(Pq, Pk, Pv, xb);

  cvt_bf16<<<nW4 / 256, 256, 0, stream>>>(Wp, Wb, nW4);
  gemm_p<<<dim3(EMB / 128, ROWSM / 128), 256, 0, stream>>>(xb, Wb, (float*)d_out, bp);
}